// Round 3
// baseline (1320.254 us; speedup 1.0000x reference)
//
#include <hip/hip_runtime.h>
#include <math.h>

typedef unsigned short u16;
typedef unsigned int   u32;

#define NROWS 32768   // BS*NAG
#define NAG 8
#define HID 256
#define INP 128
#define G3  768
#define NACT 16
#define MESS 64
#define TRAJD 80
#define CAT 264        // HID+NAG
#define QIJK 320       // HID+MESS
#define QD 64
#define HOFF 524288    // element offset of h inside d_out (q is 32768*16)

// ---- ws layout in FLOATS (canonical fp32 copies of everything) ----
#define WS_TRAJ  0          // 32768*80 = 2,621,440
#define WS_WTFC1 2621440    // [128][256]
#define WS_WTIH  2654208    // [256][768]
#define WS_WTHH  2850816    // [256][768]
#define WS_WTTR  3047424    // [264][256]
#define WS_DECW  3115008    // [16][256]
#define WS_QIJW  3119104    // [16][320]
#define WS_QW    3124224    // [64][80]  (QW,KW,VW contiguous)
#define WS_KW    3129344
#define WS_VW    3134464
#define WS_CB    3139584    // packed biases, 2272 floats
#define WS_FLAG  3141856    // int flag: 1 = inputs are fp32, 0 = bf16
// total 12,567,428 bytes

// packed bias offsets within WS_CB
#define OB_FC1B 0
#define OB_BIH  256
#define OB_BHH  1024
#define OB_DECB 1792
#define OB_TRB  1808
#define OB_QIJB 2064
#define OB_QB   2080   // QB,KB,VB contiguous stride 64

__device__ __forceinline__ float bf2f(u16 v){ return __uint_as_float(((u32)v)<<16); }
__device__ __forceinline__ u16 f2bf(float f){
    u32 u = __float_as_uint(f);
    return (u16)((u + 0x7fffu + ((u>>16)&1u))>>16);   // RNE
}
__device__ __forceinline__ float sig_(float x){ return 1.0f/(1.0f+expf(-x)); }
__device__ __forceinline__ float ldin(const void* p, size_t i, int f32){
    return f32 ? ((const float*)p)[i] : bf2f(((const u16*)p)[i]);
}
__device__ __forceinline__ void stout2(void* out, size_t i, float v0, float v1, int f32){
    if (f32){ ((float*)out)[i]=v0; ((float*)out)[i+1]=v1; }
    else    { *(u32*)((u16*)out + i) = (u32)f2bf(v0) | ((u32)f2bf(v1)<<16); }
}
__device__ __forceinline__ void stout1(void* out, size_t i, float v, int f32){
    if (f32) ((float*)out)[i]=v; else ((u16*)out)[i]=f2bf(v);
}

// ---------------- k_det: sniff input dtype ----------------
// fp32 data read as bf16 low-halves => random exponents => huge/NaN values.
__global__ void k_det(const void* __restrict__ inp, int* __restrict__ flag){
    __shared__ int cnt;
    if (threadIdx.x==0) cnt=0;
    __syncthreads();
    int big=0;
    for (int i=threadIdx.x;i<128;i+=64){
        u32 w = ((const u32*)inp)[i];
        float g = bf2f((u16)w);            // low half
        if (!(fabsf(g) <= 1e4f)) big++;    // catches NaN too
    }
    if (big) atomicAdd(&cnt, big);
    __syncthreads();
    if (threadIdx.x==0) *flag = (cnt>=4) ? 1 : 0;
}

// ---------------- k0: canonicalize all weights/biases to fp32 in ws ----------------
__global__ __launch_bounds__(256) void k0_prep(
    const void* fc1_w, const void* w_ih, const void* w_hh, const void* trans_w,
    const void* dec_w, const void* qij_w, const void* q_w, const void* k_w, const void* v_w,
    const void* fc1_b, const void* b_ih, const void* b_hh, const void* dec_b,
    const void* trans_b, const void* qij_b, const void* q_b, const void* k_b, const void* v_b,
    float* __restrict__ ws, const int* __restrict__ flagp)
{
    const int f32 = *flagp;
    int i = blockIdx.x*256 + threadIdx.x;
    if (i < 32768){ int c=i>>7, k=i&127; ws[WS_WTFC1 + k*HID + c] = ldin(fc1_w,i,f32); }
    if (i < 196608){ int r=i>>8, k=i&255;
        ws[WS_WTIH + k*G3 + r] = ldin(w_ih,i,f32);
        ws[WS_WTHH + k*G3 + r] = ldin(w_hh,i,f32); }
    if (i < 67584){ int c=i/CAT, k=i%CAT; ws[WS_WTTR + k*HID + c] = ldin(trans_w,i,f32); }
    if (i < 4096) ws[WS_DECW+i] = ldin(dec_w,i,f32);
    if (i < 5120){
        ws[WS_QIJW+i]=ldin(qij_w,i,f32);
        ws[WS_QW+i]  =ldin(q_w,i,f32);
        ws[WS_KW+i]  =ldin(k_w,i,f32);
        ws[WS_VW+i]  =ldin(v_w,i,f32); }
    if (i < 2272){
        float v;
        if      (i<256)  v=ldin(fc1_b,i,f32);
        else if (i<1024) v=ldin(b_ih,i-256,f32);
        else if (i<1792) v=ldin(b_hh,i-1024,f32);
        else if (i<1808) v=ldin(dec_b,i-1792,f32);
        else if (i<2064) v=ldin(trans_b,i-1808,f32);
        else if (i<2080) v=ldin(qij_b,i-2064,f32);
        else if (i<2144) v=ldin(q_b,i-2080,f32);
        else if (i<2208) v=ldin(k_b,i-2144,f32);
        else             v=ldin(v_b,i-2208,f32);
        ws[WS_CB+i]=v;
    }
}

// dot over stride-256 LDS activations vs two fp32 weight matrices (stride G3)
__device__ __forceinline__ void dots2f(
    const float* __restrict__ SA, const float* __restrict__ SB,
    const float* __restrict__ wA, const float* __restrict__ wB, int rb, int c0,
    float aA0[8], float aA1[8], float aB0[8], float aB1[8])
{
    #pragma unroll
    for (int i=0;i<8;i++){ aA0[i]=0.f; aA1[i]=0.f; aB0[i]=0.f; aB1[i]=0.f; }
    for (int k4=0;k4<HID/4;k4++){
        float2 a0=*(const float2*)(wA+(size_t)(4*k4+0)*G3+c0);
        float2 a1=*(const float2*)(wA+(size_t)(4*k4+1)*G3+c0);
        float2 a2=*(const float2*)(wA+(size_t)(4*k4+2)*G3+c0);
        float2 a3=*(const float2*)(wA+(size_t)(4*k4+3)*G3+c0);
        float2 b0=*(const float2*)(wB+(size_t)(4*k4+0)*G3+c0);
        float2 b1=*(const float2*)(wB+(size_t)(4*k4+1)*G3+c0);
        float2 b2=*(const float2*)(wB+(size_t)(4*k4+2)*G3+c0);
        float2 b3=*(const float2*)(wB+(size_t)(4*k4+3)*G3+c0);
        #pragma unroll
        for (int i=0;i<8;i++){
            float4 a=*(const float4*)(SA+(size_t)(rb+i)*HID+4*k4);
            aA0[i]+=a.x*a0.x+a.y*a1.x+a.z*a2.x+a.w*a3.x;
            aA1[i]+=a.x*a0.y+a.y*a1.y+a.z*a2.y+a.w*a3.y;
            float4 b=*(const float4*)(SB+(size_t)(rb+i)*HID+4*k4);
            aB0[i]+=b.x*b0.x+b.y*b1.x+b.z*b2.x+b.w*b3.x;
            aB1[i]+=b.x*b0.y+b.y*b1.y+b.z*b2.y+b.w*b3.y;
        }
    }
}

// ---------------- k12: fc1 + GRU + 5-step rollout, hc resident in LDS ----------------
__global__ __launch_bounds__(256) void k12_gru_rollout(
    const void* __restrict__ inp, const void* __restrict__ oldh,
    float* __restrict__ ws, void* __restrict__ dout, const int* __restrict__ flagp)
{
    __shared__ __align__(16) float pool[10576];
    float* s_in  = pool;            // [16][128] phase1
    float* s_x   = pool + 2048;     // [16][256] phase1
    float* s_oh  = pool + 6144;     // [16][256] phase1
    float* s_hc  = pool;            // [16][264] phase2
    float* s_dec = pool + 6144;     // [16][260] phase2
    float* s_q   = pool + 10304;    // [16][16]
    float* s_am  = pool + 10560;    // [16]

    const int f32 = *flagp;
    const float* cb    = ws + WS_CB;
    const float* wtfc1 = ws + WS_WTFC1;
    const float* wtih  = ws + WS_WTIH;
    const float* wthh  = ws + WS_WTHH;
    const float* wttr  = ws + WS_WTTR;
    const float* decw  = ws + WS_DECW;
    float* traj = ws + WS_TRAJ;

    const int t = threadIdx.x;
    const int row0 = blockIdx.x * 16;   // 2 batches per block
    const int rb = (t>>7)*8;            // row group 0 or 8
    const int c0 = (t&127)*2;           // even column pair

    for (int i=t;i<16*INP;i+=256){ int r=i>>7,k=i&127; s_in[r*INP+k]=ldin(inp,(size_t)(row0+r)*INP+k,f32); }
    for (int i=t;i<16*HID;i+=256){ int r=i>>8,k=i&255; s_oh[r*HID+k]=ldin(oldh,(size_t)(row0+r)*HID+k,f32); }
    __syncthreads();

    // ---- fc1 + relu -> s_x ----
    {
        float ax0[8], ax1[8];
        #pragma unroll
        for (int i=0;i<8;i++){ ax0[i]=0.f; ax1[i]=0.f; }
        for (int k4=0;k4<INP/4;k4++){
            float2 w0=*(const float2*)(wtfc1+(size_t)(4*k4+0)*HID+c0);
            float2 w1=*(const float2*)(wtfc1+(size_t)(4*k4+1)*HID+c0);
            float2 w2=*(const float2*)(wtfc1+(size_t)(4*k4+2)*HID+c0);
            float2 w3=*(const float2*)(wtfc1+(size_t)(4*k4+3)*HID+c0);
            #pragma unroll
            for (int i=0;i<8;i++){
                float4 a=*(const float4*)(s_in+(size_t)(rb+i)*INP+4*k4);
                ax0[i]+=a.x*w0.x+a.y*w1.x+a.z*w2.x+a.w*w3.x;
                ax1[i]+=a.x*w0.y+a.y*w1.y+a.z*w2.y+a.w*w3.y;
            }
        }
        float fb0=cb[OB_FC1B+c0], fb1=cb[OB_FC1B+c0+1];
        #pragma unroll
        for (int i=0;i<8;i++){
            float v0=ax0[i]+fb0, v1=ax1[i]+fb1;
            s_x[(size_t)(rb+i)*HID+c0]  =v0>0.f?v0:0.f;
            s_x[(size_t)(rb+i)*HID+c0+1]=v1>0.f?v1:0.f;
        }
    }
    __syncthreads();

    // ---- GRU gates -> h in regs ----
    float h0[8], h1[8];
    {
        float aA0[8],aA1[8],aB0[8],aB1[8],rg0[8],rg1[8],nv0[8],nv1[8];
        dots2f(s_x, s_oh, wtih + 0*HID, wthh + 0*HID, rb, c0, aA0,aA1,aB0,aB1);  // r
        {
            float bi0=cb[OB_BIH+c0], bi1=cb[OB_BIH+c0+1];
            float bh0=cb[OB_BHH+c0], bh1=cb[OB_BHH+c0+1];
            #pragma unroll
            for (int i=0;i<8;i++){
                rg0[i]=sig_(aA0[i]+bi0+aB0[i]+bh0);
                rg1[i]=sig_(aA1[i]+bi1+aB1[i]+bh1);
            }
        }
        dots2f(s_x, s_oh, wtih + 2*HID, wthh + 2*HID, rb, c0, aA0,aA1,aB0,aB1);  // n
        {
            float bi0=cb[OB_BIH+512+c0], bi1=cb[OB_BIH+512+c0+1];
            float bh0=cb[OB_BHH+512+c0], bh1=cb[OB_BHH+512+c0+1];
            #pragma unroll
            for (int i=0;i<8;i++){
                nv0[i]=tanhf(aA0[i]+bi0 + rg0[i]*(aB0[i]+bh0));
                nv1[i]=tanhf(aA1[i]+bi1 + rg1[i]*(aB1[i]+bh1));
            }
        }
        dots2f(s_x, s_oh, wtih + 1*HID, wthh + 1*HID, rb, c0, aA0,aA1,aB0,aB1);  // z
        {
            float bi0=cb[OB_BIH+256+c0], bi1=cb[OB_BIH+256+c0+1];
            float bh0=cb[OB_BHH+256+c0], bh1=cb[OB_BHH+256+c0+1];
            #pragma unroll
            for (int i=0;i<8;i++){
                float z0=sig_(aA0[i]+bi0+aB0[i]+bh0);
                float z1=sig_(aA1[i]+bi1+aB1[i]+bh1);
                h0[i]=(1.f-z0)*nv0[i] + z0*s_oh[(size_t)(rb+i)*HID+c0];
                h1[i]=(1.f-z1)*nv1[i] + z1*s_oh[(size_t)(rb+i)*HID+c0+1];
            }
        }
    }
    // h -> output (dtype per flag)
    #pragma unroll
    for (int i=0;i<8;i++){
        size_t ro=(size_t)(row0+rb+i)*HID + c0;
        stout2(dout, HOFF+ro, h0[i], h1[i], f32);
    }
    __syncthreads();   // done reading s_in/s_x/s_oh

    // phase 2: hc <- h ; stage dec_w fp32
    #pragma unroll
    for (int i=0;i<8;i++){
        s_hc[(size_t)(rb+i)*CAT+c0]  =h0[i];
        s_hc[(size_t)(rb+i)*CAT+c0+1]=h1[i];
    }
    for (int i=t;i<NACT*HID;i+=256){ int a=i>>8,k=i&255; s_dec[(size_t)a*260+k]=decw[i]; }
    __syncthreads();

    // ---- rollout: 5 x (dec -> argmax -> trans) ----
    const int rr=t>>4, aa=t&15;
    for (int s=0;s<5;s++){
        float acc=cb[OB_DECB+aa];
        for (int k4=0;k4<HID/4;k4++){
            float4 hv=*(const float4*)(s_hc+(size_t)rr*CAT+4*k4);
            float4 dv=*(const float4*)(s_dec+(size_t)aa*260+4*k4);
            acc += hv.x*dv.x + hv.y*dv.y + hv.z*dv.z + hv.w*dv.w;
        }
        traj[(size_t)(row0+rr)*TRAJD + s*NACT + aa] = acc;
        if (s==4) break;
        s_q[rr*16+aa]=acc;
        __syncthreads();
        if (t<16){
            float m=s_q[t*16]; int mi=0;
            #pragma unroll
            for (int a=1;a<NACT;a++){ float v=s_q[t*16+a]; if (v>m){m=v;mi=a;} }
            s_am[t]=(float)mi;
        }
        __syncthreads();
        if (t<128){ int r2=t>>3,j=t&7; s_hc[(size_t)r2*CAT+256+j]=s_am[(r2&8)+j]; }
        __syncthreads();
        float tc0[8], tc1[8];
        {
            float tb0=cb[OB_TRB+c0], tb1=cb[OB_TRB+c0+1];
            #pragma unroll
            for (int i=0;i<8;i++){ tc0[i]=tb0; tc1[i]=tb1; }
        }
        for (int k4=0;k4<CAT/4;k4++){
            float2 w0=*(const float2*)(wttr+(size_t)(4*k4+0)*HID+c0);
            float2 w1=*(const float2*)(wttr+(size_t)(4*k4+1)*HID+c0);
            float2 w2=*(const float2*)(wttr+(size_t)(4*k4+2)*HID+c0);
            float2 w3=*(const float2*)(wttr+(size_t)(4*k4+3)*HID+c0);
            #pragma unroll
            for (int i=0;i<8;i++){
                float4 a=*(const float4*)(s_hc+(size_t)(rb+i)*CAT+4*k4);
                tc0[i]+=a.x*w0.x+a.y*w1.x+a.z*w2.x+a.w*w3.x;
                tc1[i]+=a.x*w0.y+a.y*w1.y+a.z*w2.y+a.w*w3.y;
            }
        }
        __syncthreads();   // all reads of s_hc done
        #pragma unroll
        for (int i=0;i<8;i++){
            s_hc[(size_t)(rb+i)*CAT+c0]  =tc0[i];
            s_hc[(size_t)(rb+i)*CAT+c0+1]=tc1[i];
        }
        __syncthreads();
    }
}

// ---------------- k4: attention + heads, 4 batches per block ----------------
__global__ __launch_bounds__(256) void k4_attn(
    const float* __restrict__ ws, void* __restrict__ dout, const int* __restrict__ flagp)
{
    __shared__ float s_w3[3][QD][81];   // padded stride 81 (odd) - conflict-free
    __shared__ float s_dec[NACT][257];
    __shared__ float s_qij[NACT][321];
    __shared__ float s_traj[NAG][TRAJD];
    __shared__ float s_h[NAG][HID];
    __shared__ float s_qkv[3][NAG][MESS];
    __shared__ float s_att[NAG][NAG];
    __shared__ float s_msg[NAG][MESS];

    const int f32 = *flagp;
    const int t = threadIdx.x;
    const float* cb = ws + WS_CB;
    const float* traj = ws + WS_TRAJ;

    for (int i=t;i<3*QD*TRAJD;i+=256){ int w=i/5120, rem=i%5120, d=rem/80, j=rem%80; s_w3[w][d][j]=ws[WS_QW+i]; }
    for (int i=t;i<NACT*HID;i+=256)  s_dec[i>>8][i&255]=ws[WS_DECW+i];
    for (int i=t;i<NACT*QIJK;i+=256) s_qij[i/320][i%320]=ws[WS_QIJW+i];

    for (int b=0;b<4;b++){
        const int row0 = (blockIdx.x*4 + b)*NAG;
        __syncthreads();   // staging done (b=0) / prev iteration reads done
        for (int i=t;i<NAG*TRAJD;i+=256) s_traj[i/80][i%80]=traj[(size_t)row0*TRAJD+i];
        for (int i=t;i<NAG*HID;i+=256)  s_h[i>>8][i&255]=ldin(dout,(size_t)HOFF+(size_t)row0*HID+i,f32);
        __syncthreads();

        for (int o=t;o<3*NAG*QD;o+=256){      // query/key/value
            int which=o/(NAG*QD), rem=o%(NAG*QD), n=rem>>6, d=rem&63;
            float acc=cb[OB_QB + which*64 + d];
            for (int j=0;j<TRAJD;j++) acc += s_traj[n][j]*s_w3[which][d][j];
            s_qkv[which][n][d]=acc;
        }
        __syncthreads();
        if (t<NAG*NAG){                        // scores / sqrt(MESS)
            int n=t>>3,m=t&7;
            float acc=0.f;
            for (int d=0;d<MESS;d++) acc += s_qkv[0][n][d]*s_qkv[1][m][d];
            s_att[n][m]=acc*0.125f;
        }
        __syncthreads();
        if (t<NAG){                            // softmax over m
            float m=s_att[t][0];
            #pragma unroll
            for (int j=1;j<NAG;j++) m=fmaxf(m,s_att[t][j]);
            float e[NAG]; float sum=0.f;
            #pragma unroll
            for (int j=0;j<NAG;j++){ e[j]=expf(s_att[t][j]-m); sum+=e[j]; }
            float inv=1.f/sum;
            #pragma unroll
            for (int j=0;j<NAG;j++) s_att[t][j]=e[j]*inv;
        }
        __syncthreads();
        for (int o=t;o<NAG*MESS;o+=256){       // message
            int n=o>>6,d=o&63;
            float acc=0.f;
            #pragma unroll
            for (int m=0;m<NAG;m++) acc += s_att[n][m]*s_qkv[2][m][d];
            s_msg[n][d]=acc;
        }
        __syncthreads();
        if (t<NAG*NACT){                       // q = q_local + 0.5*q_ij
            int r=t>>4,a=t&15;
            float ql=cb[OB_DECB+a];
            float qi=cb[OB_QIJB+a];
            for (int k=0;k<HID;k++){
                float hv=s_h[r][k];
                ql += hv*s_dec[a][k];
                qi += hv*s_qij[a][k];
            }
            for (int m=0;m<MESS;m++) qi += s_msg[r][m]*s_qij[a][HID+m];
            stout1(dout, (size_t)(row0+r)*NACT+a, ql + 0.5f*qi, f32);
        }
    }
}

extern "C" void kernel_launch(void* const* d_in, const int* in_sizes, int n_in,
                              void* d_out, int out_size, void* d_ws, size_t ws_size,
                              hipStream_t stream)
{
    (void)in_sizes; (void)n_in; (void)out_size; (void)ws_size;
    const void* inputs = d_in[0];
    const void* oldh   = d_in[1];
    float* ws = (float*)d_ws;
    int* flagp = (int*)(ws + WS_FLAG);

    k_det<<<1,64,0,stream>>>(inputs, flagp);
    k0_prep<<<768,256,0,stream>>>(d_in[2],d_in[4],d_in[5],d_in[10],
                                  d_in[8],d_in[12],d_in[14],d_in[16],d_in[18],
                                  d_in[3],d_in[6],d_in[7],d_in[9],
                                  d_in[11],d_in[13],d_in[15],d_in[17],d_in[19],
                                  ws, flagp);
    k12_gru_rollout<<<2048,256,0,stream>>>(inputs, oldh, ws, d_out, flagp);
    k4_attn<<<1024,256,0,stream>>>(ws, d_out, flagp);
}